// Round 14
// baseline (263.969 us; speedup 1.0000x reference)
//
#include <hip/hip_runtime.h>

#define NN 64
#define BB 8
#define HH 64
#define WW 64
#define EE 513
#define EQF -0.1f
#define IMG 4096
#define CHW 12288

typedef unsigned short u16;
typedef __attribute__((ext_vector_type(8))) short bf16x8;
typedef __attribute__((ext_vector_type(4))) float f32x4;

// actsI: bf16 [node][b][padded_row 0..66][w 0..63][ci4]; rows 0,65,66 zero
#define ROWS_P 67
#define B_STR (ROWS_P * 256)      // 17152 u16 per (n,b) image
#define N_STR (BB * B_STR)        // 137216 u16 per node

#define ZR_B 6656                 // per-wave epilogue zbuf [2][64][13] f32
#define SCSR_OFF (4 * ZR_B)       // 26624
#define MAXE 64

__device__ __forceinline__ u16 f2bf(float f) {
  union { float f; unsigned u; } c; c.f = f;
  return (u16)((c.u + 0x7fffu + ((c.u >> 16) & 1u)) >> 16);
}

__device__ __forceinline__ bf16x8 mk_a(uint2 v) {
  union { uint2 u; short4 s; } cv; cv.u = v;
  bf16x8 a;
  a[0] = cv.s.x; a[1] = cv.s.y; a[2] = cv.s.z; a[3] = cv.s.w;
  a[4] = 0; a[5] = 0; a[6] = 0; a[7] = 0;
  return a;
}

// ============ fused pre-kernel: block0=CSR, blocks1-65=wfrag, rest=prep+epilogue-base ============
__global__ __launch_bounds__(512) void pre_k(const float* __restrict__ conv_w,
                                             const float* __restrict__ conv_b,
                                             const int* __restrict__ src,
                                             const int* __restrict__ dst,
                                             const float* __restrict__ states,
                                             const float* __restrict__ noise,
                                             const float* __restrict__ res,
                                             u16* __restrict__ actsI,
                                             u16* __restrict__ wfrag,
                                             int* __restrict__ csr_off,
                                             int2* __restrict__ csr2,
                                             float* __restrict__ nodeBias,
                                             int* __restrict__ nodePerm,
                                             float* __restrict__ out) {
  __shared__ int sdst[EE];
  __shared__ int ssrc[EE];
  __shared__ int swcnt[8][64];
  __shared__ int spw[8][64];
  __shared__ int soffs[NN + 1];
  __shared__ int slist[EE];
  const int tid = threadIdx.x;
  const int bid = blockIdx.x;

  if (bid == 0) {
    // ---- parallel CSR build (deterministic: preserves edge order) ----
    for (int e = tid; e < EE; e += 512) { sdst[e] = dst[e]; ssrc[e] = src[e]; }
    __syncthreads();
    const int wv = tid >> 6, l = tid & 63;
    const int d = sdst[tid];          // edge = tid (0..511); edge 512 special-cased
    int rank = 0, cnt = 0;
    for (int i = 0; i < 64; ++i) {
      int di = __shfl(d, i, 64);
      rank += (di == d && i < l) ? 1 : 0;
      cnt  += (di == l) ? 1 : 0;
    }
    swcnt[wv][l] = cnt;
    __syncthreads();
    if (tid < 64) {
      int s = 0;
      #pragma unroll
      for (int w2 = 0; w2 < 8; ++w2) { spw[w2][tid] = s; s += swcnt[w2][tid]; }
      int tot = s + ((sdst[512] == tid) ? 1 : 0);
      int scan = tot;
      #pragma unroll
      for (int ofs = 1; ofs < 64; ofs <<= 1) {
        int v = __shfl_up(scan, ofs, 64);
        if (tid >= ofs) scan += v;
      }
      soffs[tid] = scan - tot;        // exclusive offset
      if (tid == 63) soffs[64] = scan;
      // heavy-node-first permutation (locality-preserving tail smoothing)
      int prank = 0;
      #pragma unroll
      for (int m = 0; m < 64; ++m) {
        int cm = __shfl(tot, m, 64);
        prank += (cm > tot || (cm == tot && m < tid)) ? 1 : 0;
      }
      nodePerm[prank] = tid;
    }
    __syncthreads();
    slist[soffs[d] + spw[wv][d] + rank] = tid;
    if (tid == 0) { int d5 = sdst[512]; slist[soffs[d5 + 1] - 1] = 512; }
    __syncthreads();
    if (tid <= NN) csr_off[tid] = soffs[tid];
    for (int q = tid; q < EE; q += 512) {
      int ee = slist[q];
      csr2[q] = make_int2(ssrc[ee] * N_STR, ee * 512);
    }
    if (tid < 192) {
      int n = tid / 3, co = tid - n * 3;
      float s = 0.f;
      for (int q = soffs[n]; q < soffs[n + 1]; ++q)
        s += conv_b[slist[q] * 3 + co];
      nodeBias[tid] = s;
    }
  } else if (bid <= 65) {
    // ---- per-edge B-fragments: wfrag[e][lane(g,col)][j] = W[co][ci=j][kh=g][kw] ----
    int gid = (bid - 1) * 512 + tid;
    if (gid < EE * 64) {
      int e = gid >> 6, l = gid & 63;
      int g = l >> 4, col = l & 15, co = col >> 2, kw = col & 3;
      u16 v[8];
      #pragma unroll
      for (int j = 0; j < 8; ++j) {
        float f = 0.0f;
        if (co < 3 && j < 3) f = conv_w[e * 144 + co * 48 + j * 16 + g * 4 + kw];
        v[j] = f2bf(f);
      }
      uint4 pk;
      pk.x = (unsigned)v[0] | ((unsigned)v[1] << 16);
      pk.y = (unsigned)v[2] | ((unsigned)v[3] << 16);
      pk.z = (unsigned)v[4] | ((unsigned)v[5] << 16);
      pk.w = (unsigned)v[6] | ((unsigned)v[7] << 16);
      *(uint4*)(wfrag + (size_t)gid * 8) = pk;
    }
  } else {
    // ---- acts = sigmoid(states+noise) -> padded ci-interleaved bf16; out = epilogue base ----
    int idx = (bid - 66) * 512 + tid;          // 532480 exact
    int w4 = idx & 15, h = (idx >> 4) & 63, b = (idx >> 10) & 7, n = idx >> 13;
    int pbase = (n * 8 + b) * CHW + h * 64 + w4 * 4;
    float4 s0 = *(const float4*)(states + pbase);
    float4 s1 = *(const float4*)(states + pbase + IMG);
    float4 s2 = *(const float4*)(states + pbase + 2 * IMG);
    float4 z0 = *(const float4*)(noise + pbase);
    float4 z1 = *(const float4*)(noise + pbase + IMG);
    float4 z2 = *(const float4*)(noise + pbase + 2 * IMG);
    float a0[4], a1[4], a2[4];
    #pragma unroll
    for (int p = 0; p < 4; ++p) {
      float v0 = ((const float*)&s0)[p] + ((const float*)&z0)[p];
      float v1 = ((const float*)&s1)[p] + ((const float*)&z1)[p];
      float v2 = ((const float*)&s2)[p] + ((const float*)&z2)[p];
      a0[p] = 1.0f / (1.0f + __expf(-v0));
      a1[p] = 1.0f / (1.0f + __expf(-v1));
      a2[p] = 1.0f / (1.0f + __expf(-v2));
    }
    uint4 q0, q1;
    q0.x = (unsigned)f2bf(a0[0]) | ((unsigned)f2bf(a1[0]) << 16);
    q0.y = (unsigned)f2bf(a2[0]);
    q0.z = (unsigned)f2bf(a0[1]) | ((unsigned)f2bf(a1[1]) << 16);
    q0.w = (unsigned)f2bf(a2[1]);
    q1.x = (unsigned)f2bf(a0[2]) | ((unsigned)f2bf(a1[2]) << 16);
    q1.y = (unsigned)f2bf(a2[2]);
    q1.z = (unsigned)f2bf(a0[3]) | ((unsigned)f2bf(a1[3]) << 16);
    q1.w = (unsigned)f2bf(a2[3]);
    u16* dp = actsI + (size_t)((n * 8 + b) * ROWS_P + (h + 1)) * 256 + w4 * 16;
    *(uint4*)dp = q0;
    *(uint4*)(dp + 8) = q1;
    uint4 zz; zz.x = 0u; zz.y = 0u; zz.z = 0u; zz.w = 0u;
    if (h == 0) {
      u16* zp = actsI + (size_t)((n * 8 + b) * ROWS_P + 0) * 256 + w4 * 16;
      *(uint4*)zp = zz; *(uint4*)(zp + 8) = zz;
    }
    if (h == 63) {
      u16* zp = actsI + (size_t)((n * 8 + b) * ROWS_P + 65) * 256 + w4 * 16;
      *(uint4*)zp = zz; *(uint4*)(zp + 8) = zz;
      zp += 256;
      *(uint4*)zp = zz; *(uint4*)(zp + 8) = zz;
    }
    if (n == NN) {   // virtual node: out = states (agg is 0 there)
      *(float4*)(out + pbase) = s0;
      *(float4*)(out + pbase + IMG) = s1;
      *(float4*)(out + pbase + 2 * IMG) = s2;
    } else {
      // epilogue base: out = st + |res|*(EQ - st); conv adds agg+bias via RMW
      float4 r0 = *(const float4*)(res + pbase);
      float4 r1 = *(const float4*)(res + pbase + IMG);
      float4 r2 = *(const float4*)(res + pbase + 2 * IMG);
      float4 o0, o1, o2;
      #pragma unroll
      for (int p = 0; p < 4; ++p) {
        ((float*)&o0)[p] = ((const float*)&s0)[p] + fabsf(((const float*)&r0)[p]) * (EQF - ((const float*)&s0)[p]);
        ((float*)&o1)[p] = ((const float*)&s1)[p] + fabsf(((const float*)&r1)[p]) * (EQF - ((const float*)&s1)[p]);
        ((float*)&o2)[p] = ((const float*)&s2)[p] + fabsf(((const float*)&r2)[p]) * (EQF - ((const float*)&s2)[p]);
      }
      *(float4*)(out + pbase) = o0;
      *(float4*)(out + pbase + IMG) = o1;
      *(float4*)(out + pbase + 2 * IMG) = o2;
    }
  }
}

// ============ conv: registers-direct A-fragments, no LDS in loop, ring-of-3 ============
__global__ __launch_bounds__(256, 4) void conv_k(const u16* __restrict__ actsI,
                                                 const u16* __restrict__ wfrag,
                                                 const int* __restrict__ csr_off,
                                                 const int2* __restrict__ csr2g,
                                                 const float* __restrict__ nodeBias,
                                                 const int* __restrict__ nodePerm,
                                                 float* __restrict__ out) {
  __shared__ __align__(16) char smem[SCSR_OFF + MAXE * 8];   // 27136 B

  const int tid = threadIdx.x, lane = tid & 63, wid = tid >> 6;
  const int gw = blockIdx.x * 4 + wid;         // 16384 waves; 256 consecutive per node
  const int n = nodePerm[blockIdx.x >> 6];     // all 4 waves in block share n
  const int b = (gw >> 5) & 7, ht2 = gw & 31;
  const int R = ht2 * 2;                       // padded-row base of this wave's 2 output rows

  const int e0 = csr_off[n], cnt = csr_off[n + 1] - e0;
  int2* scsr = (int2*)(smem + SCSR_OFF);
  for (int q = tid; q < cnt; q += 256) scsr[q] = csr2g[e0 + q];
  __syncthreads();                             // once, before pipeline

  const int g = lane >> 4, px = lane & 15;
  // per-lane A-base (u16): fragments at + h2*256 + t*64 (compile-time immediates)
  const int pg = b * B_STR + (R + g) * 256 + px * 4;

  f32x4 acc[2][4];
  #pragma unroll
  for (int h2 = 0; h2 < 2; ++h2)
    #pragma unroll
    for (int t = 0; t < 4; ++t) { acc[h2][t][0]=0.f; acc[h2][t][1]=0.f; acc[h2][t][2]=0.f; acc[h2][t][3]=0.f; }

  uint2 qA0,qA1,qA2,qA3,qA4,qA5,qA6,qA7; bf16x8 wA;
  uint2 qB0,qB1,qB2,qB3,qB4,qB5,qB6,qB7; bf16x8 wB;
  uint2 qC0,qC1,qC2,qC3,qC4,qC5,qC6,qC7; bf16x8 wC;

#define ISSUE(P, WF_, I_) do {                                                \
    int2 c_ = scsr[(I_)];                                                     \
    int sx_ = __builtin_amdgcn_readfirstlane(c_.x);                           \
    int wx_ = __builtin_amdgcn_readfirstlane(c_.y);                           \
    const u16* ap_ = actsI + sx_ + pg;                                        \
    P##0 = *(const uint2*)(ap_ + 0);                                          \
    P##1 = *(const uint2*)(ap_ + 64);                                         \
    P##2 = *(const uint2*)(ap_ + 128);                                        \
    P##3 = *(const uint2*)(ap_ + 192);                                        \
    P##4 = *(const uint2*)(ap_ + 256);                                        \
    P##5 = *(const uint2*)(ap_ + 320);                                        \
    P##6 = *(const uint2*)(ap_ + 384);                                        \
    P##7 = *(const uint2*)(ap_ + 448);                                        \
    WF_ = *(const bf16x8*)(wfrag + wx_ + lane * 8);                           \
  } while (0)

#define COMP(P, WF_) do {                                                     \
    acc[0][0] = __builtin_amdgcn_mfma_f32_16x16x32_bf16(mk_a(P##0), WF_, acc[0][0], 0, 0, 0); \
    acc[0][1] = __builtin_amdgcn_mfma_f32_16x16x32_bf16(mk_a(P##1), WF_, acc[0][1], 0, 0, 0); \
    acc[0][2] = __builtin_amdgcn_mfma_f32_16x16x32_bf16(mk_a(P##2), WF_, acc[0][2], 0, 0, 0); \
    acc[0][3] = __builtin_amdgcn_mfma_f32_16x16x32_bf16(mk_a(P##3), WF_, acc[0][3], 0, 0, 0); \
    acc[1][0] = __builtin_amdgcn_mfma_f32_16x16x32_bf16(mk_a(P##4), WF_, acc[1][0], 0, 0, 0); \
    acc[1][1] = __builtin_amdgcn_mfma_f32_16x16x32_bf16(mk_a(P##5), WF_, acc[1][1], 0, 0, 0); \
    acc[1][2] = __builtin_amdgcn_mfma_f32_16x16x32_bf16(mk_a(P##6), WF_, acc[1][2], 0, 0, 0); \
    acc[1][3] = __builtin_amdgcn_mfma_f32_16x16x32_bf16(mk_a(P##7), WF_, acc[1][3], 0, 0, 0); \
  } while (0)

// compute edge i from set CUR; issue edge i+2 into set NXT (3 sets alive)
#define PH(CUR, WC_, NXT, WN_) do {                                           \
    if (i + 2 < cnt) ISSUE(NXT, WN_, i + 2);                                  \
    COMP(CUR, WC_);                                                           \
  } while (0)

  if (cnt > 0) {
    ISSUE(qA, wA, 0);
    if (cnt > 1) ISSUE(qB, wB, 1);
    int i = 0;
    while (true) {
      PH(qA, wA, qC, wC); if (++i == cnt) break;
      PH(qB, wB, qA, wA); if (++i == cnt) break;
      PH(qC, wC, qB, wB); if (++i == cnt) break;
    }
  }

  // ---- epilogue: wave-private kw-combine + RMW out (same-wave LDS, no barrier) ----
  float* zr = (float*)(smem + wid * ZR_B);     // [2][64][13] f32
  const float bc0 = nodeBias[n * 3 + 0];
  const float bc1 = nodeBias[n * 3 + 1];
  const float bc2 = nodeBias[n * 3 + 2];
  const int col = lane & 15;
  if (col < 12) {
    #pragma unroll
    for (int h2 = 0; h2 < 2; ++h2)
      #pragma unroll
      for (int t = 0; t < 4; ++t)
        #pragma unroll
        for (int r = 0; r < 4; ++r)
          zr[(h2 * 64 + t * 16 + g * 4 + r) * 13 + col] = acc[h2][t][r];
  }
  #pragma unroll
  for (int h2 = 0; h2 < 2; ++h2) {
    const int hr = R + h2;
    #pragma unroll
    for (int co = 0; co < 3; ++co) {
      float y = (co == 0) ? bc0 : ((co == 1) ? bc1 : bc2);
      #pragma unroll
      for (int kw = 0; kw < 4; ++kw) {
        int wp = lane + kw - 1;
        if (wp >= 0 && wp < 64) y += zr[(h2 * 64 + wp) * 13 + co * 4 + kw];
      }
      int o = ((n * 8 + b) * 3 + co) * IMG + hr * 64 + lane;
      out[o] += y;     // base (st + |res|(EQ-st)) written by pre_k
    }
  }
}

extern "C" void kernel_launch(void* const* d_in, const int* in_sizes, int n_in,
                              void* d_out, int out_size, void* d_ws, size_t ws_size,
                              hipStream_t stream) {
  const float* states = (const float*)d_in[0];
  const float* noise  = (const float*)d_in[1];
  const float* conv_w = (const float*)d_in[2];
  const float* conv_b = (const float*)d_in[3];
  const float* res    = (const float*)d_in[4];
  const int*   src    = (const int*)d_in[5];
  const int*   dst    = (const int*)d_in[6];
  float* out = (float*)d_out;

  u16* actsI = (u16*)d_ws;                                   // 17,838,080 B
  u16* wfrag = (u16*)((char*)d_ws + 17838080);               // 525,312 B -> 18,363,392
  int* csr_off = (int*)((char*)d_ws + 18363392);             // 320 B -> 18,363,712
  int2* csr2 = (int2*)((char*)d_ws + 18363712);              // 4,104 B -> 18,367,816
  float* nodeBias = (float*)((char*)d_ws + 18367816);        // 768 B -> 18,368,584
  int* nodePerm = (int*)((char*)d_ws + 18368584);            // 256 B

  pre_k<<<1106, 512, 0, stream>>>(conv_w, conv_b, src, dst, states, noise, res,
                                  actsI, wfrag, csr_off, csr2, nodeBias, nodePerm, out);
  conv_k<<<4096, 256, 0, stream>>>(actsI, wfrag, csr_off, csr2, nodeBias, nodePerm, out);
}

// Round 15
// 49.852 us; speedup vs baseline: 5.2950x; 5.2950x over previous
//
#include <hip/hip_runtime.h>

#define NN 64
#define BB 8
#define HH 64
#define WW 64
#define EE 513
#define EQF -0.1f
#define IMG 4096
#define CHW 12288

typedef unsigned short u16;
typedef __attribute__((ext_vector_type(8))) short bf16x8;
typedef __attribute__((ext_vector_type(4))) float f32x4;

// actsI: bf16 [node][b][padded_row 0..66][w 0..63][ci4]; rows 0,65,66 zero
#define ROWS_P 67
#define B_STR (ROWS_P * 256)      // 17152 u16 per (n,b) image
#define N_STR (BB * B_STR)        // 137216 u16 per node

#define TROW_B 528                // LDS tile row stride (bytes)
#define TILE_B (11 * TROW_B)      // 5808 B per buffer (11 rows)
#define NPIECE 352                // 11 rows * 32 x 16B pieces

__device__ __forceinline__ u16 f2bf(float f) {
  union { float f; unsigned u; } c; c.f = f;
  return (u16)((c.u + 0x7fffu + ((c.u >> 16) & 1u)) >> 16);
}

// barrier that does NOT drain vmcnt (T4): prefetched global loads stay in flight
__device__ __forceinline__ void wg_barrier() {
  asm volatile("s_waitcnt lgkmcnt(0)\n\ts_barrier" ::: "memory");
  __builtin_amdgcn_sched_barrier(0);
}

// ============ fused pre-kernel: block0=CSR, blocks1-65=wfrag, rest=prep+epilogue-base ============
__global__ __launch_bounds__(512) void pre_k(const float* __restrict__ conv_w,
                                             const float* __restrict__ conv_b,
                                             const int* __restrict__ src,
                                             const int* __restrict__ dst,
                                             const float* __restrict__ states,
                                             const float* __restrict__ noise,
                                             const float* __restrict__ res,
                                             u16* __restrict__ actsI,
                                             u16* __restrict__ wfrag,
                                             int* __restrict__ csr_off,
                                             int2* __restrict__ csr2,
                                             float* __restrict__ nodeBias,
                                             int* __restrict__ nodePerm,
                                             float* __restrict__ out) {
  __shared__ int sdst[EE];
  __shared__ int ssrc[EE];
  __shared__ int swcnt[8][64];
  __shared__ int spw[8][64];
  __shared__ int soffs[NN + 1];
  __shared__ int slist[EE];
  const int tid = threadIdx.x;
  const int bid = blockIdx.x;

  if (bid == 0) {
    // ---- parallel CSR build (deterministic: preserves edge order) ----
    for (int e = tid; e < EE; e += 512) { sdst[e] = dst[e]; ssrc[e] = src[e]; }
    __syncthreads();
    const int wv = tid >> 6, l = tid & 63;
    const int d = sdst[tid];          // edge = tid (0..511); edge 512 special-cased
    int rank = 0, cnt = 0;
    for (int i = 0; i < 64; ++i) {
      int di = __shfl(d, i, 64);
      rank += (di == d && i < l) ? 1 : 0;
      cnt  += (di == l) ? 1 : 0;
    }
    swcnt[wv][l] = cnt;               // count of node l within wave wv
    __syncthreads();
    if (tid < 64) {
      int s = 0;
      #pragma unroll
      for (int w2 = 0; w2 < 8; ++w2) { spw[w2][tid] = s; s += swcnt[w2][tid]; }
      int tot = s + ((sdst[512] == tid) ? 1 : 0);
      int scan = tot;
      #pragma unroll
      for (int ofs = 1; ofs < 64; ofs <<= 1) {
        int v = __shfl_up(scan, ofs, 64);
        if (tid >= ofs) scan += v;
      }
      soffs[tid] = scan - tot;        // exclusive offset
      if (tid == 63) soffs[64] = scan;
      // heavy-node-first permutation (locality-preserving tail smoothing)
      int prank = 0;
      #pragma unroll
      for (int m = 0; m < 64; ++m) {
        int cm = __shfl(tot, m, 64);
        prank += (cm > tot || (cm == tot && m < tid)) ? 1 : 0;
      }
      nodePerm[prank] = tid;
    }
    __syncthreads();
    slist[soffs[d] + spw[wv][d] + rank] = tid;
    if (tid == 0) { int d5 = sdst[512]; slist[soffs[d5 + 1] - 1] = 512; }  // 512 is last
    __syncthreads();
    if (tid <= NN) csr_off[tid] = soffs[tid];
    for (int q = tid; q < EE; q += 512) {
      int ee = slist[q];
      csr2[q] = make_int2(ssrc[ee] * N_STR, ee * 512);
    }
    if (tid < 192) {
      int n = tid / 3, co = tid - n * 3;
      float s = 0.f;
      for (int q = soffs[n]; q < soffs[n + 1]; ++q)
        s += conv_b[slist[q] * 3 + co];
      nodeBias[tid] = s;
    }
  } else if (bid <= 65) {
    // ---- per-edge B-fragments: wfrag[e][lane(g,col)][j] = W[co][ci=j][kh=g][kw] ----
    int gid = (bid - 1) * 512 + tid;
    if (gid < EE * 64) {
      int e = gid >> 6, l = gid & 63;
      int g = l >> 4, col = l & 15, co = col >> 2, kw = col & 3;
      u16 v[8];
      #pragma unroll
      for (int j = 0; j < 8; ++j) {
        float f = 0.0f;
        if (co < 3 && j < 3) f = conv_w[e * 144 + co * 48 + j * 16 + g * 4 + kw];
        v[j] = f2bf(f);
      }
      uint4 pk;
      pk.x = (unsigned)v[0] | ((unsigned)v[1] << 16);
      pk.y = (unsigned)v[2] | ((unsigned)v[3] << 16);
      pk.z = (unsigned)v[4] | ((unsigned)v[5] << 16);
      pk.w = (unsigned)v[6] | ((unsigned)v[7] << 16);
      *(uint4*)(wfrag + (size_t)gid * 8) = pk;
    }
  } else {
    // ---- acts = sigmoid(states+noise) -> padded ci-interleaved bf16; out = epilogue base ----
    int idx = (bid - 66) * 512 + tid;          // 532480 exact
    int w4 = idx & 15, h = (idx >> 4) & 63, b = (idx >> 10) & 7, n = idx >> 13;
    int pbase = (n * 8 + b) * CHW + h * 64 + w4 * 4;
    float4 s0 = *(const float4*)(states + pbase);
    float4 s1 = *(const float4*)(states + pbase + IMG);
    float4 s2 = *(const float4*)(states + pbase + 2 * IMG);
    float4 z0 = *(const float4*)(noise + pbase);
    float4 z1 = *(const float4*)(noise + pbase + IMG);
    float4 z2 = *(const float4*)(noise + pbase + 2 * IMG);
    float a0[4], a1[4], a2[4];
    #pragma unroll
    for (int p = 0; p < 4; ++p) {
      float v0 = ((const float*)&s0)[p] + ((const float*)&z0)[p];
      float v1 = ((const float*)&s1)[p] + ((const float*)&z1)[p];
      float v2 = ((const float*)&s2)[p] + ((const float*)&z2)[p];
      a0[p] = 1.0f / (1.0f + __expf(-v0));
      a1[p] = 1.0f / (1.0f + __expf(-v1));
      a2[p] = 1.0f / (1.0f + __expf(-v2));
    }
    uint4 q0, q1;
    q0.x = (unsigned)f2bf(a0[0]) | ((unsigned)f2bf(a1[0]) << 16);
    q0.y = (unsigned)f2bf(a2[0]);
    q0.z = (unsigned)f2bf(a0[1]) | ((unsigned)f2bf(a1[1]) << 16);
    q0.w = (unsigned)f2bf(a2[1]);
    q1.x = (unsigned)f2bf(a0[2]) | ((unsigned)f2bf(a1[2]) << 16);
    q1.y = (unsigned)f2bf(a2[2]);
    q1.z = (unsigned)f2bf(a0[3]) | ((unsigned)f2bf(a1[3]) << 16);
    q1.w = (unsigned)f2bf(a2[3]);
    u16* dp = actsI + (size_t)((n * 8 + b) * ROWS_P + (h + 1)) * 256 + w4 * 16;
    *(uint4*)dp = q0;
    *(uint4*)(dp + 8) = q1;
    uint4 zz; zz.x = 0u; zz.y = 0u; zz.z = 0u; zz.w = 0u;
    if (h == 0) {
      u16* zp = actsI + (size_t)((n * 8 + b) * ROWS_P + 0) * 256 + w4 * 16;
      *(uint4*)zp = zz; *(uint4*)(zp + 8) = zz;
    }
    if (h == 63) {
      u16* zp = actsI + (size_t)((n * 8 + b) * ROWS_P + 65) * 256 + w4 * 16;
      *(uint4*)zp = zz; *(uint4*)(zp + 8) = zz;
      zp += 256;
      *(uint4*)zp = zz; *(uint4*)(zp + 8) = zz;
    }
    if (n == NN) {   // virtual node: out = states (agg is 0 there)
      *(float4*)(out + pbase) = s0;
      *(float4*)(out + pbase + IMG) = s1;
      *(float4*)(out + pbase + 2 * IMG) = s2;
    } else {
      // epilogue base: out = st + |res|*(EQ - st); conv adds agg+bias via RMW
      float4 r0 = *(const float4*)(res + pbase);
      float4 r1 = *(const float4*)(res + pbase + IMG);
      float4 r2 = *(const float4*)(res + pbase + 2 * IMG);
      float4 o0, o1, o2;
      #pragma unroll
      for (int p = 0; p < 4; ++p) {
        ((float*)&o0)[p] = ((const float*)&s0)[p] + fabsf(((const float*)&r0)[p]) * (EQF - ((const float*)&s0)[p]);
        ((float*)&o1)[p] = ((const float*)&s1)[p] + fabsf(((const float*)&r1)[p]) * (EQF - ((const float*)&s1)[p]);
        ((float*)&o2)[p] = ((const float*)&s2)[p] + fabsf(((const float*)&r2)[p]) * (EQF - ((const float*)&s2)[p]);
      }
      *(float4*)(out + pbase) = o0;
      *(float4*)(out + pbase + IMG) = o1;
      *(float4*)(out + pbase + 2 * IMG) = o2;
    }
  }
}

// ============ conv: 8-row blocks, high occupancy, RMW epilogue (R11 champion) ============
__global__ __launch_bounds__(256, 5) void conv_k(const u16* __restrict__ actsI,
                                                 const u16* __restrict__ wfrag,
                                                 const int* __restrict__ csr_off,
                                                 const int2* __restrict__ csr2,
                                                 const float* __restrict__ nodeBias,
                                                 const int* __restrict__ nodePerm,
                                                 float* __restrict__ out) {
  __shared__ __align__(16) char smem[13312];   // 2*TILE_B=11616 tiles; 4*3328 zr

  const int tid = threadIdx.x, lane = tid & 63, wid = tid >> 6;
  const int bid = blockIdx.x;
  // n-major locality: 64 consecutive blocks share n; heavy nodes first
  const int n = nodePerm[bid >> 6];
  const int b = (bid >> 3) & 7, ht = bid & 7;
  const int R0 = ht * 8;

  // staging: 352 x 16B pieces; thread handles piece tid (+ tid+256 for tid<96)
  int pg[2], pl[2];
  #pragma unroll
  for (int j = 0; j < 2; ++j) {
    int p = tid + j * 256;
    int row = p >> 5, c16 = p & 31;
    pg[j] = b * B_STR + (R0 + row) * 256 + c16 * 8;   // u16 units (padded rows: no bounds checks)
    pl[j] = row * TROW_B + c16 * 16;                  // bytes
  }
  const bool pv1 = tid < (NPIECE - 256);

  const int g = lane >> 4, px = lane & 15;
  const int abase = (wid * 2 + g) * TROW_B + px * 8;  // + h2*TROW_B + t*128

  f32x4 acc[2][4];
  #pragma unroll
  for (int h2 = 0; h2 < 2; ++h2)
    #pragma unroll
    for (int t = 0; t < 4; ++t) { acc[h2][t][0]=0.f; acc[h2][t][1]=0.f; acc[h2][t][2]=0.f; acc[h2][t][3]=0.f; }

  const int e0 = csr_off[n], cnt = csr_off[n + 1] - e0;
  const float bc0 = nodeBias[n * 3 + 0];
  const float bc1 = nodeBias[n * 3 + 1];
  const float bc2 = nodeBias[n * 3 + 2];

  uint4 a0, a1; bf16x8 wa;
  uint4 b0, b1; bf16x8 wb;

#define LOADP(R0_,R1_,WF_,I_) do {                                            \
    int2 c_ = csr2[e0 + (I_)];                                                \
    int sx_ = __builtin_amdgcn_readfirstlane(c_.x);                           \
    int wx_ = __builtin_amdgcn_readfirstlane(c_.y);                           \
    const u16* ap_ = actsI + sx_;                                             \
    R0_ = *(const uint4*)(ap_ + pg[0]);                                       \
    if (pv1) R1_ = *(const uint4*)(ap_ + pg[1]);                              \
    WF_ = *(const bf16x8*)(wfrag + wx_ + lane * 8);                           \
  } while (0)

#define STOREP(R0_,R1_,BOFS_) do {                                            \
    *(uint4*)(smem + (BOFS_) + pl[0]) = R0_;                                  \
    if (pv1) *(uint4*)(smem + (BOFS_) + pl[1]) = R1_;                         \
  } while (0)

#define COMP(BOFS_,WF_) do {                                                  \
    _Pragma("unroll")                                                         \
    for (int h2_ = 0; h2_ < 2; ++h2_) {                                       \
      _Pragma("unroll")                                                       \
      for (int t_ = 0; t_ < 4; ++t_) {                                        \
        short4 d_ = *(const short4*)(smem + (BOFS_) + abase + h2_ * TROW_B + t_ * 128); \
        bf16x8 av_;                                                           \
        av_[0]=d_.x; av_[1]=d_.y; av_[2]=d_.z; av_[3]=d_.w;                   \
        av_[4]=0; av_[5]=0; av_[6]=0; av_[7]=0;                               \
        acc[h2_][t_] = __builtin_amdgcn_mfma_f32_16x16x32_bf16(av_, WF_, acc[h2_][t_], 0, 0, 0); \
      }                                                                       \
    }                                                                         \
  } while (0)

#define PHASE(R0_,R1_,WF_,NEXTI_) do {                                        \
    STOREP(R0_, R1_, bofs);                                                   \
    bf16x8 wcur_ = WF_;                                                       \
    if ((NEXTI_) < cnt) LOADP(R0_, R1_, WF_, (NEXTI_));                       \
    wg_barrier();                                                             \
    COMP(bofs, wcur_);                                                        \
    bofs ^= TILE_B;                                                           \
  } while (0)

  if (cnt > 0) LOADP(a0, a1, wa, 0);
  if (cnt > 1) LOADP(b0, b1, wb, 1);
  int bofs = 0;
  int i = 0;
  for (; i + 1 < cnt; i += 2) {
    PHASE(a0, a1, wa, i + 2);
    PHASE(b0, b1, wb, i + 3);
  }
  if (i < cnt) PHASE(a0, a1, wa, cnt);

  // ---- epilogue: prefetch out RMW values, then per-wave kw-combine ----
  __syncthreads();                          // tiles dead; reuse smem per-wave
  int obase[6]; float oval[6];
  #pragma unroll
  for (int h2 = 0; h2 < 2; ++h2)
    #pragma unroll
    for (int co = 0; co < 3; ++co) {
      int ix = h2 * 3 + co;
      obase[ix] = ((n * 8 + b) * 3 + co) * IMG + (R0 + wid * 2 + h2) * 64 + lane;
      oval[ix] = out[obase[ix]];            // issued before zr writes; drains under LDS epilogue
    }
  float* zr = (float*)(smem + wid * 3328);  // [64 px][13] f32
  const int col = lane & 15;
  #pragma unroll
  for (int h2 = 0; h2 < 2; ++h2) {
    if (col < 12) {
      #pragma unroll
      for (int t = 0; t < 4; ++t)
        #pragma unroll
        for (int r = 0; r < 4; ++r)
          zr[(t * 16 + g * 4 + r) * 13 + col] = acc[h2][t][r];
    }
    #pragma unroll
    for (int co = 0; co < 3; ++co) {
      float y = (co == 0) ? bc0 : ((co == 1) ? bc1 : bc2);
      #pragma unroll
      for (int kw = 0; kw < 4; ++kw) {
        int wp = lane + kw - 1;
        if (wp >= 0 && wp < 64) y += zr[wp * 13 + co * 4 + kw];
      }
      int ix = h2 * 3 + co;
      out[obase[ix]] = oval[ix] + y;        // base (st + |res|(EQ-st)) written by pre_k
    }
  }
}

extern "C" void kernel_launch(void* const* d_in, const int* in_sizes, int n_in,
                              void* d_out, int out_size, void* d_ws, size_t ws_size,
                              hipStream_t stream) {
  const float* states = (const float*)d_in[0];
  const float* noise  = (const float*)d_in[1];
  const float* conv_w = (const float*)d_in[2];
  const float* conv_b = (const float*)d_in[3];
  const float* res    = (const float*)d_in[4];
  const int*   src    = (const int*)d_in[5];
  const int*   dst    = (const int*)d_in[6];
  float* out = (float*)d_out;

  u16* actsI = (u16*)d_ws;                                   // 17,838,080 B
  u16* wfrag = (u16*)((char*)d_ws + 17838080);               // 525,312 B -> 18,363,392
  int* csr_off = (int*)((char*)d_ws + 18363392);             // 320 B -> 18,363,712
  int2* csr2 = (int2*)((char*)d_ws + 18363712);              // 4,104 B -> 18,367,816
  float* nodeBias = (float*)((char*)d_ws + 18367816);        // 768 B -> 18,368,584
  int* nodePerm = (int*)((char*)d_ws + 18368584);            // 256 B

  pre_k<<<1106, 512, 0, stream>>>(conv_w, conv_b, src, dst, states, noise, res,
                                  actsI, wfrag, csr_off, csr2, nodeBias, nodePerm, out);
  conv_k<<<4096, 256, 0, stream>>>(actsI, wfrag, csr_off, csr2, nodeBias, nodePerm, out);
}